// Round 9
// baseline (178.027 us; speedup 1.0000x reference)
//
#include <hip/hip_runtime.h>
#include <hip/hip_bf16.h>
#include <cstdint>
#include <cstddef>

// ---------------- types ----------------
typedef __attribute__((ext_vector_type(8))) short     bf16x8;
typedef __attribute__((ext_vector_type(4))) float     f32x4;
typedef __attribute__((ext_vector_type(4))) unsigned short u16x4;

using as1_void = __attribute__((address_space(1))) void;
using as3_void = __attribute__((address_space(3))) void;

#define MFMA16(a,b,c) __builtin_amdgcn_mfma_f32_16x16x32_bf16((a),(b),(c),0,0,0)

__device__ __forceinline__ unsigned short f2bf(float f) {
  union { float f; unsigned u; } v; v.f = f;
  unsigned r = v.u + 0x7fffu + ((v.u >> 16) & 1u);
  return (unsigned short)(r >> 16);
}
__device__ __forceinline__ float bf2f(unsigned short h) {
  union { unsigned u; float f; } v; v.u = ((unsigned)h) << 16; return v.f;
}
__device__ __forceinline__ unsigned cvt_pk_bf16(float lo, float hi) {
  unsigned r;
  asm volatile("v_cvt_pk_bf16_f32 %0, %1, %2" : "=v"(r) : "v"(lo), "v"(hi));
  return r;
}
// A&S 7.1.26 minimax erf, |err| <= 1.5e-7 (exact at bf16 scale)
__device__ __forceinline__ float fast_erf(float x) {
  float ax = fabsf(x);
  float t = __builtin_amdgcn_rcpf(fmaf(0.3275911f, ax, 1.0f));
  float p = fmaf(1.061405429f, t, -1.453152027f);
  p = fmaf(p, t, 1.421413741f);
  p = fmaf(p, t, -0.284496736f);
  p = fmaf(p, t, 0.254829592f);
  p = p * t;
  float e = __builtin_amdgcn_exp2f(-ax * ax * 1.44269504f);
  float r = fmaf(-p, e, 1.0f);
  return copysignf(r, x);
}

__device__ __forceinline__ void gload16(const void* g, void* l) {
  __builtin_amdgcn_global_load_lds((const as1_void*)g, (as3_void*)l, 16, 0, 0);
}

// ---------------- problem constants ----------------
// B=2, U1=U2=3072, IF=256, FD=256, M=4, D=64
constexpr size_t oXq  = 0;                       // (unused)
constexpr size_t oXk  = oXq + 1572864ull * 2;    // (unused)
constexpr size_t oWq  = oXk + 1572864ull * 2;    // bf16 [256*256]
constexpr size_t oWv  = oWq + 65536ull   * 2;    // bf16 [1024*256]
constexpr size_t oWm  = oWv + 262144ull  * 2;    // bf16 [256*256]
constexpr size_t oWo  = oWm + 65536ull   * 2;    // bf16 [256*256]
constexpr size_t oQb  = oWo + 65536ull   * 2;    // bf16 [8][3072][64]  (q/8)
constexpr size_t oKb  = oQb + 1572864ull * 2;    // bf16 [8][3072][64]
constexpr size_t oVb  = oKb + 1572864ull * 2;    // bf16 [8][256][3072] (V^T)
constexpr size_t oPa  = oVb + 6291456ull * 2;    // bf16 [2][8][3072][256] O partials
constexpr size_t oMl  = oPa + 12582912ull * 2;   // f32  [2][8][3072][2]  (m,l)

// ================= kernel 1: f32 -> bf16 conversion (weights only) ===========
__global__ __launch_bounds__(256) void cvtw_kernel(
    const float* __restrict__ wq, const float* __restrict__ wv,
    const float* __restrict__ wm, const float* __restrict__ wo,
    char* __restrict__ wsb) {
  int i4 = (blockIdx.x * 256 + threadIdx.x) * 4;   // over 458752 elems
  const float* src; size_t dsto; int local;
  if (i4 < 65536)        { src = wq; dsto = oWq; local = i4; }
  else if (i4 < 327680)  { src = wv; dsto = oWv; local = i4 - 65536; }
  else if (i4 < 393216)  { src = wm; dsto = oWm; local = i4 - 327680; }
  else                   { src = wo; dsto = oWo; local = i4 - 393216; }
  f32x4 v = *(const f32x4*)(src + local);
  u16x4 o;
  o.x = f2bf(v.x); o.y = f2bf(v.y); o.z = f2bf(v.z); o.w = f2bf(v.w);
  *(u16x4*)((unsigned short*)(wsb + dsto) + local) = o;
}

// ================= kernel 2: projections q,k,v (fused cvt, 64-row blocks) ====
__global__ __launch_bounds__(256, 2) void proj_kernel(
    const float* __restrict__ qf32, const float* __restrict__ kf32,
    const float* __restrict__ bv, char* __restrict__ wsb) {
  __shared__ unsigned short sA[64 * 256];   // 32KB bf16 (chunk-swizzled)

  const int lane = threadIdx.x & 63, wid = threadIdx.x >> 6;
  const int lq = lane & 15, hi = lane >> 4;
  const int ny = blockIdx.x % 6;
  const int r0 = (blockIdx.x / 6) * 64;

  const float* Xf = (ny == 0) ? qf32 : kf32;
  const unsigned short* W;
  if (ny <= 1) W = (const unsigned short*)(wsb + oWq);
  else         W = (const unsigned short*)(wsb + oWv) + (size_t)(ny - 2) * 256 * 256;

  // ---- stage A: 64 rows f32 -> bf16 LDS (coalesced, swizzled) ----
  {
    const int t = threadIdx.x;
#pragma unroll
    for (int j = 0; j < 16; ++j) {
      int flat = j * 256 + t;            // f32x4 units over [64][64]
      int row = flat >> 6;
      int c4 = flat & 63;
      f32x4 v = *(const f32x4*)(Xf + ((size_t)(r0 + row) * 256 + c4 * 4));
      u16x4 o;
      o.x = f2bf(v.x); o.y = f2bf(v.y); o.z = f2bf(v.z); o.w = f2bf(v.w);
      int col = c4 * 4;
      int c8 = col >> 3;
      *(u16x4*)&sA[row * 256 + (((c8 ^ (row & 7)) << 3) + (col & 7))] = o;
    }
  }
  __syncthreads();

  const int n0 = wid * 64;

  // ---- GEMM: 64 rows x this wave's 64 cols, K=256 ----
  f32x4 acc[4][4];   // [rg][bt]
#pragma unroll
  for (int rg = 0; rg < 4; ++rg)
#pragma unroll
    for (int bt = 0; bt < 4; ++bt) acc[rg][bt] = (f32x4){0.f, 0.f, 0.f, 0.f};

#pragma unroll
  for (int ks = 0; ks < 8; ++ks) {
    bf16x8 a[4];
#pragma unroll
    for (int rg = 0; rg < 4; ++rg)
      a[rg] = *(const bf16x8*)&sA[(rg * 16 + lq) * 256 + (((ks * 4 + hi) ^ (lq & 7)) << 3)];
#pragma unroll
    for (int bt = 0; bt < 4; ++bt) {
      int n = n0 + bt * 16 + lq;
      bf16x8 bfr = *(const bf16x8*)(W + (size_t)n * 256 + ks * 32 + hi * 8);
#pragma unroll
      for (int rg = 0; rg < 4; ++rg) acc[rg][bt] = MFMA16(a[rg], bfr, acc[rg][bt]);
    }
  }

  const int b = r0 / 3072, u0 = r0 % 3072;

  if (ny <= 1) {
    unsigned short* outp = (unsigned short*)(wsb + (ny == 0 ? oQb : oKb));
    float scale = (ny == 0) ? 0.125f : 1.0f;
    int m = wid;
#pragma unroll
    for (int bt = 0; bt < 4; ++bt) {
      int d = bt * 16 + lq;
#pragma unroll
      for (int rg = 0; rg < 4; ++rg) {
        int ub = u0 + rg * 16 + hi * 4;
#pragma unroll
        for (int r = 0; r < 4; ++r) {
          outp[((size_t)(b * 4 + m) * 3072 + (ub + r)) * 64 + d] = f2bf(acc[rg][bt][r] * scale);
        }
      }
    }
  } else {
    unsigned short* vbT = (unsigned short*)(wsb + oVb);
    int mchunk = ny - 2;
#pragma unroll
    for (int bt = 0; bt < 4; ++bt) {
      int f = n0 + bt * 16 + lq;
      float bias = bv[mchunk * 256 + f];
#pragma unroll
      for (int rg = 0; rg < 4; ++rg) {
        int ub = u0 + rg * 16 + hi * 4;
        u16x4 pk;
#pragma unroll
        for (int r = 0; r < 4; ++r) pk[r] = f2bf(acc[rg][bt][r] + bias);
        *(u16x4*)(vbT + ((size_t)(b * 4 + mchunk) * 256 + f) * 3072 + ub) = pk;
      }
    }
  }
}

// ================= kernel 3: flash attention (K in regs, 2 barriers/tile) ====
// grid 768 x 256 (4 waves): bm = bid&7 (XCD pin), z = bid>>3: qt = z>>1 (64 q),
// kvh = z&1 (kv half, 24 tiles of 64).
// K-fragments: direct global->reg, prefetched 1 tile ahead (issued after
// bar-A, consumed next iter). No sK, no bar1.
// Per tile: issue V(8) -> QK(kc regs)/softmax/pack -> vmcnt(0)+lgkm bar-A
// -> prefetch kc(t+1) -> rescale+PV -> lgkm bar-B.
__global__ __launch_bounds__(256, 3) void attn_kernel(char* __restrict__ wsb) {
  __shared__ unsigned short sV[256 * 64];       // 32KB [f][kv]  chunk-swizzled
  __shared__ unsigned short sP[4][16 * 64];     // 8KB  [g]      P^T
  __shared__ float sCr[4];
  __shared__ float sInv[4][16];

  const int lane = threadIdx.x & 63, wid = threadIdx.x >> 6;
  const int lq = lane & 15, hi = lane >> 4;
  const int lr3 = lane >> 3, lc3 = lane & 7;
  const int fh = wid >> 1, gp = wid & 1;
  const int bm = blockIdx.x & 7;
  const int z = blockIdx.x >> 3;
  const int qt = z >> 1, kvh = z & 1;
  const int q0 = qt * 64;
  const int kvbase = kvh * 1536;
  const int key = lq & 7;

  const unsigned short* qb = (const unsigned short*)(wsb + oQb) + (size_t)bm * 3072 * 64;
  const unsigned short* kb = (const unsigned short*)(wsb + oKb) + (size_t)bm * 3072 * 64;
  const unsigned short* vb = (const unsigned short*)(wsb + oVb) + (size_t)bm * 256 * 3072;

  // persistent Q B-frags (q = q0 + wid*16 + lq)
  const unsigned short* qp = qb + (size_t)(q0 + wid * 16 + lq) * 64 + hi * 8;
  const bf16x8 qf0 = *(const bf16x8*)(qp);
  const bf16x8 qf1 = *(const bf16x8*)(qp + 32);
  asm volatile("s_waitcnt vmcnt(0)" ::: "memory");   // clean counter state

  // V staging pointers (bumped per tile)
  const unsigned short* pv[8];
  unsigned short* dv[8];
#pragma unroll
  for (int i = 0; i < 8; ++i) {
    int ch = i * 4 + wid;
    int f = ch * 8 + lr3;
    int cs = lc3 ^ (f & 7);
    pv[i] = vb + (size_t)f * 3072 + kvbase + cs * 8;
    dv[i] = &sV[ch * 512];
  }

  // K fragment pointer (direct global reads): row kv = kvbase + t*16 + lq
  const unsigned short* kp = kb + (size_t)(kvbase + lq) * 64 + hi * 8;

  f32x4 acc[2][8];
#pragma unroll
  for (int g = 0; g < 2; ++g)
#pragma unroll
    for (int ft = 0; ft < 8; ++ft) acc[g][ft] = (f32x4){0.f, 0.f, 0.f, 0.f};
  float mrun = -1e30f, lrun = 0.f;

  char* myP = (char*)&sP[wid][0];
  const int g0 = gp * 2, g1 = gp * 2 + 1;
  char* rP0 = (char*)&sP[g0][0];
  char* rP1 = (char*)&sP[g1][0];

  // prologue: load kc for tile 0
  bf16x8 kc0[4], kc1[4];
#pragma unroll
  for (int t = 0; t < 4; ++t) {
    kc0[t] = *(const bf16x8*)(kp + (size_t)t * 1024);
    kc1[t] = *(const bf16x8*)(kp + (size_t)t * 1024 + 32);
  }
  kp += 4096;

  for (int kt = 0; kt < 24; ++kt) {
    // ---- issue V tile kt (8 chunks this wave) ----
#pragma unroll
    for (int i = 0; i < 8; ++i) { gload16(pv[i], dv[i]); pv[i] += 64; }

    // ---- QK^T from kc regs ----
    f32x4 s[4];
#pragma unroll
    for (int t = 0; t < 4; ++t) {
      f32x4 zz = (f32x4){0.f, 0.f, 0.f, 0.f};
      zz = MFMA16(kc0[t], qf0, zz);
      zz = MFMA16(kc1[t], qf1, zz);
      s[t] = zz;
    }

    // ---- lane-local online softmax ----
    float pmax = s[0][0];
#pragma unroll
    for (int t = 0; t < 4; ++t)
#pragma unroll
      for (int r = 0; r < 4; ++r) pmax = fmaxf(pmax, s[t][r]);
    pmax = fmaxf(pmax, __shfl_xor(pmax, 16));
    pmax = fmaxf(pmax, __shfl_xor(pmax, 32));

    float cr = 1.0f;
    if (__any(pmax > mrun + 8.0f)) {        // defer-max
      float mnew = fmaxf(mrun, pmax);
      cr = __builtin_amdgcn_exp2f((mrun - mnew) * 1.44269504f);
      lrun *= cr; mrun = mnew;
    }
    if (lane == 0) sCr[wid] = cr;

    const float mk = mrun * 1.44269504f;
    float ps[4][4];
    float psum = 0.f;
#pragma unroll
    for (int t = 0; t < 4; ++t)
#pragma unroll
      for (int r = 0; r < 4; ++r) {
        float p = __builtin_amdgcn_exp2f(s[t][r] * 1.44269504f - mk);
        ps[t][r] = p; psum += p;
      }
    psum += __shfl_xor(psum, 16);
    psum += __shfl_xor(psum, 32);
    lrun += psum;

    // ---- pack P^T -> sP[w] (cvt_pk, swizzled) ----
#pragma unroll
    for (int t = 0; t < 4; ++t) {
      unsigned w0 = cvt_pk_bf16(ps[t][0], ps[t][1]);
      unsigned w1 = cvt_pk_bf16(ps[t][2], ps[t][3]);
      int c = (2 * t + (hi >> 1)) ^ key;
      *(uint2*)(myP + lq * 128 + (c << 4) + ((hi & 1) << 3)) = make_uint2(w0, w1);
    }

    asm volatile("s_waitcnt vmcnt(0) lgkmcnt(0)" ::: "memory");  // V + P ready
    __builtin_amdgcn_sched_barrier(0);
    __builtin_amdgcn_s_barrier();                       // bar-A

    // ---- prefetch kc for tile kt+1 (hides under PV + bar + next QK) ----
    if (kt < 23) {
#pragma unroll
      for (int t = 0; t < 4; ++t) {
        kc0[t] = *(const bf16x8*)(kp + (size_t)t * 1024);
        kc1[t] = *(const bf16x8*)(kp + (size_t)t * 1024 + 32);
      }
      kp += 4096;
    }

    // ---- rescale (cross-wave factors) ----
    float c0 = sCr[g0], c1 = sCr[g1];
    if (c0 != 1.0f) {
#pragma unroll
      for (int ft = 0; ft < 8; ++ft) {
        acc[0][ft][0] *= c0; acc[0][ft][1] *= c0;
        acc[0][ft][2] *= c0; acc[0][ft][3] *= c0;
      }
    }
    if (c1 != 1.0f) {
#pragma unroll
      for (int ft = 0; ft < 8; ++ft) {
        acc[1][ft][0] *= c1; acc[1][ft][1] *= c1;
        acc[1][ft][2] *= c1; acc[1][ft][3] *= c1;
      }
    }

    // ---- PV on f-half fh for groups g0,g1 ----
    bf16x8 pb00 = *(const bf16x8*)(rP0 + lq * 128 + ((hi ^ key) << 4));
    bf16x8 pb01 = *(const bf16x8*)(rP0 + lq * 128 + (((4 + hi) ^ key) << 4));
    bf16x8 pb10 = *(const bf16x8*)(rP1 + lq * 128 + ((hi ^ key) << 4));
    bf16x8 pb11 = *(const bf16x8*)(rP1 + lq * 128 + (((4 + hi) ^ key) << 4));

    __builtin_amdgcn_s_setprio(1);
#pragma unroll
    for (int ft = 0; ft < 8; ++ft) {
      const unsigned short* vr = &sV[(fh * 128 + ft * 16 + lq) * 64];
      bf16x8 vf0 = *(const bf16x8*)(vr + ((hi ^ key) * 8));
      bf16x8 vf1 = *(const bf16x8*)(vr + (((4 + hi) ^ key) * 8));
      acc[0][ft] = MFMA16(vf0, pb00, acc[0][ft]);
      acc[0][ft] = MFMA16(vf1, pb01, acc[0][ft]);
      acc[1][ft] = MFMA16(vf0, pb10, acc[1][ft]);
      acc[1][ft] = MFMA16(vf1, pb11, acc[1][ft]);
    }
    __builtin_amdgcn_s_setprio(0);

    asm volatile("s_waitcnt lgkmcnt(0)" ::: "memory");
    __builtin_amdgcn_sched_barrier(0);
    __builtin_amdgcn_s_barrier();                       // bar-B
  }

  // ---- epilogue: 1/l per group; store bf16 partials + (m,l) ----
  if (hi == 0) {
    sInv[wid][lq] = 1.0f / lrun;
    float* ml = (float*)(wsb + oMl);
    size_t qi = (size_t)(kvh * 8 + bm) * 3072 + q0 + wid * 16 + lq;
    *(float2*)(ml + qi * 2) = make_float2(mrun, lrun);
  }
  __syncthreads();

  unsigned short* paB = (unsigned short*)(wsb + oPa) + (size_t)(kvh * 8 + bm) * 3072 * 256;
#pragma unroll
  for (int gi = 0; gi < 2; ++gi) {
    int g = gp * 2 + gi;
    float inv = sInv[g][lq];
    unsigned short* orow = paB + (size_t)(q0 + g * 16 + lq) * 256 + fh * 128 + hi * 4;
#pragma unroll
    for (int ft = 0; ft < 8; ++ft) {
      u16x4 pk4;
#pragma unroll
      for (int r = 0; r < 4; ++r) pk4[r] = f2bf(acc[gi][ft][r] * inv);
      *(u16x4*)(orow + ft * 16) = pk4;
    }
  }
}

// ================= kernel 4: combine + FFN + LN + mode aggregation ===========
// grid 768 = 2 b x 384 u-blocks of 8. Rows: row = du*4 + m (32 rows).
__global__ __launch_bounds__(256, 3) void ffn_kernel(char* __restrict__ wsb,
                                                     const float* __restrict__ bmid,
                                                     const float* __restrict__ bout,
                                                     const float* __restrict__ lng,
                                                     const float* __restrict__ lnb,
                                                     const float* __restrict__ wagg,
                                                     const float* __restrict__ bagg,
                                                     float* __restrict__ out) {
  __shared__ unsigned short sA[32 * 256];   // 16KB combined fused bf16 (swizzled)
  __shared__ unsigned short sM[32 * 256];   // 16KB mid bf16 (swizzled)
  __shared__ float redS[4][32], redQ[4][32], redC[4][32];
  __shared__ float sSc[32];
  __shared__ float sW0[32], sW1[32];

  const int lane = threadIdx.x & 63, wid = threadIdx.x >> 6;
  const int lq = lane & 15, hi = lane >> 4;
  const int b = blockIdx.x / 384;
  const int u0 = (blockIdx.x % 384) * 8;

  const unsigned short* Wm = (const unsigned short*)(wsb + oWm);
  const unsigned short* Wo = (const unsigned short*)(wsb + oWo);
  const unsigned short* pa = (const unsigned short*)(wsb + oPa);
  const float* mlb = (const float*)(wsb + oMl);

  // ---- combine weights per row (row = du*4 + m) ----
  if (threadIdx.x < 32) {
    int m = threadIdx.x & 3, du = threadIdx.x >> 2;
    size_t qi = (size_t)(b * 4 + m) * 3072 + u0 + du;
    float2 ml0 = *(const float2*)(mlb + qi * 2);
    float2 ml1 = *(const float2*)(mlb + (qi + 8ull * 3072) * 2);
    float M = fmaxf(ml0.x, ml1.x);
    float e0 = ml0.y * __builtin_amdgcn_exp2f((ml0.x - M) * 1.44269504f);
    float e1 = ml1.y * __builtin_amdgcn_exp2f((ml1.x - M) * 1.44269504f);
    float inv = 1.0f / (e0 + e1);
    sW0[threadIdx.x] = e0 * inv;
    sW1[threadIdx.x] = e1 * inv;
  }
  __syncthreads();

  // ---- stage combined fused rows -> sA (bf16, swizzled) ----
  {
    int t = threadIdx.x;
#pragma unroll
    for (int j = 0; j < 4; ++j) {
      int i = j * 256 + t;             // over [32 rows][32 chunks]
      int row = i >> 5, c = i & 31;
      int m = row & 3, du = row >> 2;
      const unsigned short* p0 = pa + ((size_t)(b * 4 + m) * 3072 + u0 + du) * 256 + c * 8;
      bf16x8 a = *(const bf16x8*)(p0);
      bf16x8 bb = *(const bf16x8*)(p0 + 8ull * 3072 * 256);
      float w0 = sW0[row], w1 = sW1[row];
      u16x4 oA, oB;
#pragma unroll
      for (int e = 0; e < 4; ++e) {
        oA[e] = f2bf(w0 * bf2f((unsigned short)a[e]) + w1 * bf2f((unsigned short)bb[e]));
        oB[e] = f2bf(w0 * bf2f((unsigned short)a[e + 4]) + w1 * bf2f((unsigned short)bb[e + 4]));
      }
      unsigned short* dst = &sA[row * 256 + ((c ^ (row & 7)) << 3)];
      *(u16x4*)(dst) = oA;
      *(u16x4*)(dst + 4) = oB;
    }
  }
  __syncthreads();

  const int n0 = wid * 64;
  const int rowb = hi * 4;

  // ---- GEMM1: fused @ Wm^T (32 rows, this wave's 64 cols) ----
  f32x4 acc1[2][4];
#pragma unroll
  for (int rg = 0; rg < 2; ++rg)
#pragma unroll
    for (int bt = 0; bt < 4; ++bt) acc1[rg][bt] = (f32x4){0.f, 0.f, 0.f, 0.f};
#pragma unroll
  for (int ks = 0; ks < 8; ++ks) {
    bf16x8 a[2];
#pragma unroll
    for (int rg = 0; rg < 2; ++rg)
      a[rg] = *(const bf16x8*)&sA[(rg * 16 + lq) * 256 + (((ks * 4 + hi) ^ (lq & 7)) << 3)];
#pragma unroll
    for (int bt = 0; bt < 4; ++bt) {
      int n = n0 + bt * 16 + lq;
      bf16x8 bfr = *(const bf16x8*)(Wm + (size_t)n * 256 + ks * 32 + hi * 8);
#pragma unroll
      for (int rg = 0; rg < 2; ++rg) acc1[rg][bt] = MFMA16(a[rg], bfr, acc1[rg][bt]);
    }
  }
  // gelu (fast exact erf) -> sM
#pragma unroll
  for (int bt = 0; bt < 4; ++bt) {
    int n = n0 + bt * 16 + lq;
    float bb = bmid[n];
#pragma unroll
    for (int rg = 0; rg < 2; ++rg)
#pragma unroll
      for (int r = 0; r < 4; ++r) {
        float x = acc1[rg][bt][r] + bb;
        float g = 0.5f * x * (1.0f + fast_erf(x * 0.7071067811865475f));
        int row = rg * 16 + rowb + r;
        sM[row * 256 + (((n >> 3) ^ (row & 7)) << 3) + (n & 7)] = f2bf(g);
      }
  }
  __syncthreads();

  // ---- GEMM2: mid @ Wo^T ----
  f32x4 acc2[2][4];
#pragma unroll
  for (int rg = 0; rg < 2; ++rg)
#pragma unroll
    for (int bt = 0; bt < 4; ++bt) acc2[rg][bt] = (f32x4){0.f, 0.f, 0.f, 0.f};
#pragma unroll
  for (int ks = 0; ks < 8; ++ks) {
    bf16x8 a[2];
#pragma unroll
    for (int rg = 0; rg < 2; ++rg)
      a[rg] = *(const bf16x8*)&sM[(rg * 16 + lq) * 256 + (((ks * 4 + hi) ^ (lq & 7)) << 3)];
#pragma unroll
    for (int bt = 0; bt < 4; ++bt) {
      int n = n0 + bt * 16 + lq;
      bf16x8 bfr = *(const bf16x8*)(Wo + (size_t)n * 256 + ks * 32 + hi * 8);
#pragma unroll
      for (int rg = 0; rg < 2; ++rg) acc2[rg][bt] = MFMA16(a[rg], bfr, acc2[rg][bt]);
    }
  }

  // ---- + b_out + residual; LN partial sums ----
  float sS[2][4], sQ[2][4];
#pragma unroll
  for (int rg = 0; rg < 2; ++rg)
#pragma unroll
    for (int r = 0; r < 4; ++r) { sS[rg][r] = 0.f; sQ[rg][r] = 0.f; }
#pragma unroll
  for (int bt = 0; bt < 4; ++bt) {
    int n = n0 + bt * 16 + lq;
    float bo = bout[n];
#pragma unroll
    for (int rg = 0; rg < 2; ++rg)
#pragma unroll
      for (int r = 0; r < 4; ++r) {
        int row = rg * 16 + rowb + r;
        float res = bf2f(sA[row * 256 + (((n >> 3) ^ (row & 7)) << 3) + (n & 7)]);
        float x = acc2[rg][bt][r] + bo + res;
        acc2[rg][bt][r] = x;
        sS[rg][r] += x;
        sQ[rg][r] += x * x;
      }
  }
#pragma unroll
  for (int rg = 0; rg < 2; ++rg)
#pragma unroll
    for (int r = 0; r < 4; ++r) {
#pragma unroll
      for (int off = 1; off < 16; off <<= 1) {
        sS[rg][r] += __shfl_xor(sS[rg][r], off);
        sQ[rg][r] += __shfl_xor(sQ[rg][r], off);
      }
    }
  if (lq == 0) {
#pragma unroll
    for (int rg = 0; rg < 2; ++rg)
#pragma unroll
      for (int r = 0; r < 4; ++r) {
        int row = rg * 16 + rowb + r;
        redS[wid][row] = sS[rg][r]; redQ[wid][row] = sQ[rg][r];
      }
  }
  __syncthreads();

  // ---- LN transform (in-place into acc2) + agg score partials ----
  float scp[2][4];
#pragma unroll
  for (int rg = 0; rg < 2; ++rg)
#pragma unroll
    for (int r = 0; r < 4; ++r) {
      int row = rg * 16 + rowb + r;
      float ts = redS[0][row] + redS[1][row] + redS[2][row] + redS[3][row];
      float tq = redQ[0][row] + redQ[1][row] + redQ[2][row] + redQ[3][row];
      float mean = ts * (1.0f / 256.0f);
      float var = tq * (1.0f / 256.0f) - mean * mean;
      float rs = rsqrtf(var + 1e-12f);
      float sc = 0.f;
#pragma unroll
      for (int bt = 0; bt < 4; ++bt) {
        int n = n0 + bt * 16 + lq;
        float o = (acc2[rg][bt][r] - mean) * rs * lng[n] + lnb[n];
        acc2[rg][bt][r] = o;
        sc += o * wagg[n];
      }
      scp[rg][r] = sc;
    }
#pragma unroll
  for (int rg = 0; rg < 2; ++rg)
#pragma unroll
    for (int r = 0; r < 4; ++r) {
#pragma unroll
      for (int off = 1; off < 16; off <<= 1) scp[rg][r] += __shfl_xor(scp[rg][r], off);
    }
  if (lq == 0) {
#pragma unroll
    for (int rg = 0; rg < 2; ++rg)
#pragma unroll
      for (int r = 0; r < 4; ++r) redC[wid][rg * 16 + rowb + r] = scp[rg][r];
  }
  __syncthreads();

  if (threadIdx.x < 32) {
    int t = threadIdx.x;
    sSc[t] = redC[0][t] + redC[1][t] + redC[2][t] + redC[3][t] + bagg[0];
  }
  __syncthreads();

  // ---- mode softmax + weighted sum (modes are the 4 regs r of acc2[rg]) ----
  float wm[2][4];   // [rg][m], du = rg*4 + hi
#pragma unroll
  for (int rg = 0; rg < 2; ++rg) {
    int du = rg * 4 + hi;
    float s0 = sSc[du * 4 + 0], s1 = sSc[du * 4 + 1];
    float s2 = sSc[du * 4 + 2], s3 = sSc[du * 4 + 3];
    float mx = fmaxf(fmaxf(s0, s1), fmaxf(s2, s3));
    float e0 = __builtin_amdgcn_exp2f((s0 - mx) * 1.44269504f);
    float e1 = __builtin_amdgcn_exp2f((s1 - mx) * 1.44269504f);
    float e2 = __builtin_amdgcn_exp2f((s2 - mx) * 1.44269504f);
    float e3 = __builtin_amdgcn_exp2f((s3 - mx) * 1.44269504f);
    float inv = 1.0f / (e0 + e1 + e2 + e3);
    wm[rg][0] = e0 * inv; wm[rg][1] = e1 * inv;
    wm[rg][2] = e2 * inv; wm[rg][3] = e3 * inv;
  }
#pragma unroll
  for (int bt = 0; bt < 4; ++bt) {
    int n = n0 + bt * 16 + lq;
#pragma unroll
    for (int rg = 0; rg < 2; ++rg) {
      int du = rg * 4 + hi;
      float val = wm[rg][0] * acc2[rg][bt][0] + wm[rg][1] * acc2[rg][bt][1]
                + wm[rg][2] * acc2[rg][bt][2] + wm[rg][3] * acc2[rg][bt][3];
      out[((size_t)(b * 3072 + u0 + du)) * 256 + n] = val;
    }
  }
}

// ================= launcher =================
extern "C" void kernel_launch(void* const* d_in, const int* in_sizes, int n_in,
                              void* d_out, int out_size, void* d_ws, size_t ws_size,
                              hipStream_t stream) {
  const float* q  = (const float*)d_in[0];
  const float* k  = (const float*)d_in[1];
  const float* wq = (const float*)d_in[2];
  const float* wv = (const float*)d_in[3];
  const float* bv = (const float*)d_in[4];
  const float* wm = (const float*)d_in[5];
  const float* bm = (const float*)d_in[6];
  const float* wo = (const float*)d_in[7];
  const float* bo = (const float*)d_in[8];
  const float* lg = (const float*)d_in[9];
  const float* lb = (const float*)d_in[10];
  const float* wa = (const float*)d_in[11];
  const float* ba = (const float*)d_in[12];
  char* wsb = (char*)d_ws;

  cvtw_kernel<<<448, 256, 0, stream>>>(wq, wv, wm, wo, wsb);
  proj_kernel<<<576, 256, 0, stream>>>(q, k, bv, wsb);
  attn_kernel<<<768, 256, 0, stream>>>(wsb);
  ffn_kernel<<<768, 256, 0, stream>>>(wsb, bm, bo, lg, lb, wa, ba, (float*)d_out);
}

// Round 10
// 128.323 us; speedup vs baseline: 1.3873x; 1.3873x over previous
//
#include <hip/hip_runtime.h>
#include <hip/hip_bf16.h>
#include <cstdint>
#include <cstddef>

// ---------------- types ----------------
typedef __attribute__((ext_vector_type(8))) short     bf16x8;
typedef __attribute__((ext_vector_type(4))) float     f32x4;
typedef __attribute__((ext_vector_type(4))) unsigned short u16x4;

using as1_void = __attribute__((address_space(1))) void;
using as3_void = __attribute__((address_space(3))) void;

#define MFMA16(a,b,c) __builtin_amdgcn_mfma_f32_16x16x32_bf16((a),(b),(c),0,0,0)

__device__ __forceinline__ unsigned short f2bf(float f) {
  union { float f; unsigned u; } v; v.f = f;
  unsigned r = v.u + 0x7fffu + ((v.u >> 16) & 1u);
  return (unsigned short)(r >> 16);
}
__device__ __forceinline__ float bf2f(unsigned short h) {
  union { unsigned u; float f; } v; v.u = ((unsigned)h) << 16; return v.f;
}
__device__ __forceinline__ unsigned cvt_pk_bf16(float lo, float hi) {
  unsigned r;
  asm volatile("v_cvt_pk_bf16_f32 %0, %1, %2" : "=v"(r) : "v"(lo), "v"(hi));
  return r;
}
// A&S 7.1.26 minimax erf, |err| <= 1.5e-7 (exact at bf16 scale)
__device__ __forceinline__ float fast_erf(float x) {
  float ax = fabsf(x);
  float t = __builtin_amdgcn_rcpf(fmaf(0.3275911f, ax, 1.0f));
  float p = fmaf(1.061405429f, t, -1.453152027f);
  p = fmaf(p, t, 1.421413741f);
  p = fmaf(p, t, -0.284496736f);
  p = fmaf(p, t, 0.254829592f);
  p = p * t;
  float e = __builtin_amdgcn_exp2f(-ax * ax * 1.44269504f);
  float r = fmaf(-p, e, 1.0f);
  return copysignf(r, x);
}

__device__ __forceinline__ void gload16(const void* g, void* l) {
  __builtin_amdgcn_global_load_lds((const as1_void*)g, (as3_void*)l, 16, 0, 0);
}

// ---------------- problem constants ----------------
// B=2, U1=U2=3072, IF=256, FD=256, M=4, D=64
constexpr size_t oXq  = 0;                       // (unused)
constexpr size_t oXk  = oXq + 1572864ull * 2;    // (unused)
constexpr size_t oWq  = oXk + 1572864ull * 2;    // bf16 [256*256]
constexpr size_t oWv  = oWq + 65536ull   * 2;    // bf16 [1024*256]
constexpr size_t oWm  = oWv + 262144ull  * 2;    // bf16 [256*256]
constexpr size_t oWo  = oWm + 65536ull   * 2;    // bf16 [256*256]
constexpr size_t oQb  = oWo + 65536ull   * 2;    // bf16 [8][3072][64]  (q/8)
constexpr size_t oKb  = oQb + 1572864ull * 2;    // bf16 [8][3072][64]
constexpr size_t oVb  = oKb + 1572864ull * 2;    // bf16 [8][256][3072] (V^T)
constexpr size_t oPa  = oVb + 6291456ull * 2;    // bf16 [2][8][3072][256] O partials
constexpr size_t oMl  = oPa + 12582912ull * 2;   // f32  [2][8][3072][2]  (m,l)

// ================= kernel 1: f32 -> bf16 conversion (weights only) ===========
__global__ __launch_bounds__(256) void cvtw_kernel(
    const float* __restrict__ wq, const float* __restrict__ wv,
    const float* __restrict__ wm, const float* __restrict__ wo,
    char* __restrict__ wsb) {
  int i4 = (blockIdx.x * 256 + threadIdx.x) * 4;   // over 458752 elems
  const float* src; size_t dsto; int local;
  if (i4 < 65536)        { src = wq; dsto = oWq; local = i4; }
  else if (i4 < 327680)  { src = wv; dsto = oWv; local = i4 - 65536; }
  else if (i4 < 393216)  { src = wm; dsto = oWm; local = i4 - 327680; }
  else                   { src = wo; dsto = oWo; local = i4 - 393216; }
  f32x4 v = *(const f32x4*)(src + local);
  u16x4 o;
  o.x = f2bf(v.x); o.y = f2bf(v.y); o.z = f2bf(v.z); o.w = f2bf(v.w);
  *(u16x4*)((unsigned short*)(wsb + dsto) + local) = o;
}

// ================= kernel 2: projections q,k,v (fused cvt, 64-row blocks) ====
__global__ __launch_bounds__(256, 2) void proj_kernel(
    const float* __restrict__ qf32, const float* __restrict__ kf32,
    const float* __restrict__ bv, char* __restrict__ wsb) {
  __shared__ unsigned short sA[64 * 256];   // 32KB bf16 (chunk-swizzled)

  const int lane = threadIdx.x & 63, wid = threadIdx.x >> 6;
  const int lq = lane & 15, hi = lane >> 4;
  const int ny = blockIdx.x % 6;
  const int r0 = (blockIdx.x / 6) * 64;

  const float* Xf = (ny == 0) ? qf32 : kf32;
  const unsigned short* W;
  if (ny <= 1) W = (const unsigned short*)(wsb + oWq);
  else         W = (const unsigned short*)(wsb + oWv) + (size_t)(ny - 2) * 256 * 256;

  // ---- stage A: 64 rows f32 -> bf16 LDS (coalesced, swizzled) ----
  {
    const int t = threadIdx.x;
#pragma unroll
    for (int j = 0; j < 16; ++j) {
      int flat = j * 256 + t;            // f32x4 units over [64][64]
      int row = flat >> 6;
      int c4 = flat & 63;
      f32x4 v = *(const f32x4*)(Xf + ((size_t)(r0 + row) * 256 + c4 * 4));
      u16x4 o;
      o.x = f2bf(v.x); o.y = f2bf(v.y); o.z = f2bf(v.z); o.w = f2bf(v.w);
      int col = c4 * 4;
      int c8 = col >> 3;
      *(u16x4*)&sA[row * 256 + (((c8 ^ (row & 7)) << 3) + (col & 7))] = o;
    }
  }
  __syncthreads();

  const int n0 = wid * 64;

  // ---- GEMM: 64 rows x this wave's 64 cols, K=256 ----
  f32x4 acc[4][4];   // [rg][bt]
#pragma unroll
  for (int rg = 0; rg < 4; ++rg)
#pragma unroll
    for (int bt = 0; bt < 4; ++bt) acc[rg][bt] = (f32x4){0.f, 0.f, 0.f, 0.f};

#pragma unroll
  for (int ks = 0; ks < 8; ++ks) {
    bf16x8 a[4];
#pragma unroll
    for (int rg = 0; rg < 4; ++rg)
      a[rg] = *(const bf16x8*)&sA[(rg * 16 + lq) * 256 + (((ks * 4 + hi) ^ (lq & 7)) << 3)];
#pragma unroll
    for (int bt = 0; bt < 4; ++bt) {
      int n = n0 + bt * 16 + lq;
      bf16x8 bfr = *(const bf16x8*)(W + (size_t)n * 256 + ks * 32 + hi * 8);
#pragma unroll
      for (int rg = 0; rg < 4; ++rg) acc[rg][bt] = MFMA16(a[rg], bfr, acc[rg][bt]);
    }
  }

  const int b = r0 / 3072, u0 = r0 % 3072;

  if (ny <= 1) {
    unsigned short* outp = (unsigned short*)(wsb + (ny == 0 ? oQb : oKb));
    float scale = (ny == 0) ? 0.125f : 1.0f;
    int m = wid;
#pragma unroll
    for (int bt = 0; bt < 4; ++bt) {
      int d = bt * 16 + lq;
#pragma unroll
      for (int rg = 0; rg < 4; ++rg) {
        int ub = u0 + rg * 16 + hi * 4;
#pragma unroll
        for (int r = 0; r < 4; ++r) {
          outp[((size_t)(b * 4 + m) * 3072 + (ub + r)) * 64 + d] = f2bf(acc[rg][bt][r] * scale);
        }
      }
    }
  } else {
    unsigned short* vbT = (unsigned short*)(wsb + oVb);
    int mchunk = ny - 2;
#pragma unroll
    for (int bt = 0; bt < 4; ++bt) {
      int f = n0 + bt * 16 + lq;
      float bias = bv[mchunk * 256 + f];
#pragma unroll
      for (int rg = 0; rg < 4; ++rg) {
        int ub = u0 + rg * 16 + hi * 4;
        u16x4 pk;
#pragma unroll
        for (int r = 0; r < 4; ++r) pk[r] = f2bf(acc[rg][bt][r] + bias);
        *(u16x4*)(vbT + ((size_t)(b * 4 + mchunk) * 256 + f) * 3072 + ub) = pk;
      }
    }
  }
}

// ================= kernel 3: flash attention (R7 structure, proven 73us) =====
// grid 768 x 256 (4 waves): bm = bid&7 (XCD pin), z = bid>>3: qt = z>>1 (64 q),
// kvh = z&1 (kv half, 24 tiles of 64).
// Wave w: QK^T + lane-local online softmax for group g=w (16 q-rows), pack
// P^T (cvt_pk) into shared sP[w]. Then wave w = (fh=w>>1, gp=w&1) does PV for
// f-half fh over groups gp*2, gp*2+1 (V-frag reused x2).
// Barrier schedule per tile (raw s_barrier + counted waitcnt):
//   issue V(8) -> vmcnt(8) [K landed] bar1 -> QK/SM/pack (V lands under this)
//   -> vmcnt(0) lgkmcnt(0) bar2 -> issue K(t+1) -> rescale+PV -> bar3
__global__ __launch_bounds__(256, 3) void attn_kernel(char* __restrict__ wsb) {
  __shared__ unsigned short sK[64 * 64];        // 8KB  [kv][d]  chunk-swizzled
  __shared__ unsigned short sV[256 * 64];       // 32KB [f][kv]  chunk-swizzled
  __shared__ unsigned short sP[4][16 * 64];     // 8KB  [g]      P^T
  __shared__ float sCr[4];
  __shared__ float sInv[4][16];

  const int lane = threadIdx.x & 63, wid = threadIdx.x >> 6;
  const int lq = lane & 15, hi = lane >> 4;
  const int lr3 = lane >> 3, lc3 = lane & 7;
  const int fh = wid >> 1, gp = wid & 1;
  const int bm = blockIdx.x & 7;
  const int z = blockIdx.x >> 3;
  const int qt = z >> 1, kvh = z & 1;
  const int q0 = qt * 64;
  const int kvbase = kvh * 1536;
  const int key = lq & 7;

  const unsigned short* qb = (const unsigned short*)(wsb + oQb) + (size_t)bm * 3072 * 64;
  const unsigned short* kb = (const unsigned short*)(wsb + oKb) + (size_t)bm * 3072 * 64;
  const unsigned short* vb = (const unsigned short*)(wsb + oVb) + (size_t)bm * 256 * 3072;

  // persistent Q B-frags for this wave's group (q = q0 + wid*16 + lq)
  const unsigned short* qp = qb + (size_t)(q0 + wid * 16 + lq) * 64 + hi * 8;
  const bf16x8 qf0 = *(const bf16x8*)(qp);
  const bf16x8 qf1 = *(const bf16x8*)(qp + 32);
  asm volatile("s_waitcnt vmcnt(0)" ::: "memory");   // qf resident; vmcnt clean

  // staging pointers (bumped per tile)
  const unsigned short* pk[2];
  unsigned short* dk[2];
#pragma unroll
  for (int i = 0; i < 2; ++i) {
    int ch = wid * 2 + i;
    int r = ch * 8 + lr3;
    int cs = lc3 ^ (r & 7);
    pk[i] = kb + (size_t)(kvbase + r) * 64 + cs * 8;
    dk[i] = &sK[ch * 512];
  }
  const unsigned short* pv[8];
  unsigned short* dv[8];
#pragma unroll
  for (int i = 0; i < 8; ++i) {
    int ch = i * 4 + wid;
    int f = ch * 8 + lr3;
    int cs = lc3 ^ (f & 7);
    pv[i] = vb + (size_t)f * 3072 + kvbase + cs * 8;
    dv[i] = &sV[ch * 512];
  }

  f32x4 acc[2][8];
#pragma unroll
  for (int g = 0; g < 2; ++g)
#pragma unroll
    for (int ft = 0; ft < 8; ++ft) acc[g][ft] = (f32x4){0.f, 0.f, 0.f, 0.f};
  float mrun = -1e30f, lrun = 0.f;

  char* myP = (char*)&sP[wid][0];
  const int g0 = gp * 2, g1 = gp * 2 + 1;
  char* rP0 = (char*)&sP[g0][0];
  char* rP1 = (char*)&sP[g1][0];

  // prologue: issue K tile 0
  gload16(pk[0], dk[0]); gload16(pk[1], dk[1]);
  pk[0] += 4096; pk[1] += 4096;

  for (int kt = 0; kt < 24; ++kt) {
    // ---- issue V tile kt (8 chunks this wave) ----
#pragma unroll
    for (int i = 0; i < 8; ++i) { gload16(pv[i], dv[i]); pv[i] += 64; }

    asm volatile("s_waitcnt vmcnt(8)" ::: "memory");   // K landed (V in flight)
    __builtin_amdgcn_sched_barrier(0);
    __builtin_amdgcn_s_barrier();                       // bar1

    // ---- QK^T group w: s[t][r] = S[q=lq][t*16 + hi*4 + r] ----
    bf16x8 kc0[4], kc1[4];
#pragma unroll
    for (int t = 0; t < 4; ++t) {
      const unsigned short* kr = &sK[(t * 16 + lq) * 64];
      kc0[t] = *(const bf16x8*)(kr + ((hi ^ key) * 8));
      kc1[t] = *(const bf16x8*)(kr + (((hi + 4) ^ key) * 8));
    }
    f32x4 s[4];
#pragma unroll
    for (int t = 0; t < 4; ++t) {
      f32x4 zz = (f32x4){0.f, 0.f, 0.f, 0.f};
      zz = MFMA16(kc0[t], qf0, zz);
      zz = MFMA16(kc1[t], qf1, zz);
      s[t] = zz;
    }

    // ---- lane-local online softmax ----
    float pmax = s[0][0];
#pragma unroll
    for (int t = 0; t < 4; ++t)
#pragma unroll
      for (int r = 0; r < 4; ++r) pmax = fmaxf(pmax, s[t][r]);
    pmax = fmaxf(pmax, __shfl_xor(pmax, 16));
    pmax = fmaxf(pmax, __shfl_xor(pmax, 32));

    float cr = 1.0f;
    if (__any(pmax > mrun + 8.0f)) {        // defer-max
      float mnew = fmaxf(mrun, pmax);
      cr = __builtin_amdgcn_exp2f((mrun - mnew) * 1.44269504f);
      lrun *= cr; mrun = mnew;
    }
    if (lane == 0) sCr[wid] = cr;

    const float mk = mrun * 1.44269504f;
    float ps[4][4];
    float psum = 0.f;
#pragma unroll
    for (int t = 0; t < 4; ++t)
#pragma unroll
      for (int r = 0; r < 4; ++r) {
        float p = __builtin_amdgcn_exp2f(s[t][r] * 1.44269504f - mk);
        ps[t][r] = p; psum += p;
      }
    psum += __shfl_xor(psum, 16);
    psum += __shfl_xor(psum, 32);
    lrun += psum;

    // ---- pack P^T -> sP[w] (cvt_pk, swizzled) ----
#pragma unroll
    for (int t = 0; t < 4; ++t) {
      unsigned w0 = cvt_pk_bf16(ps[t][0], ps[t][1]);
      unsigned w1 = cvt_pk_bf16(ps[t][2], ps[t][3]);
      int c = (2 * t + (hi >> 1)) ^ key;
      *(uint2*)(myP + lq * 128 + (c << 4) + ((hi & 1) << 3)) = make_uint2(w0, w1);
    }

    asm volatile("s_waitcnt vmcnt(0) lgkmcnt(0)" ::: "memory");  // V + P ready
    __builtin_amdgcn_sched_barrier(0);
    __builtin_amdgcn_s_barrier();                       // bar2

    // ---- issue K tile kt+1 (latency hides under PV) ----
    if (kt < 23) {
      gload16(pk[0], dk[0]); gload16(pk[1], dk[1]);
      pk[0] += 4096; pk[1] += 4096;
    }

    // ---- rescale (cross-wave factors) ----
    float c0 = sCr[g0], c1 = sCr[g1];
    if (c0 != 1.0f) {
#pragma unroll
      for (int ft = 0; ft < 8; ++ft) {
        acc[0][ft][0] *= c0; acc[0][ft][1] *= c0;
        acc[0][ft][2] *= c0; acc[0][ft][3] *= c0;
      }
    }
    if (c1 != 1.0f) {
#pragma unroll
      for (int ft = 0; ft < 8; ++ft) {
        acc[1][ft][0] *= c1; acc[1][ft][1] *= c1;
        acc[1][ft][2] *= c1; acc[1][ft][3] *= c1;
      }
    }

    // ---- PV on f-half fh for groups g0,g1 ----
    bf16x8 pb00 = *(const bf16x8*)(rP0 + lq * 128 + ((hi ^ key) << 4));
    bf16x8 pb01 = *(const bf16x8*)(rP0 + lq * 128 + (((4 + hi) ^ key) << 4));
    bf16x8 pb10 = *(const bf16x8*)(rP1 + lq * 128 + ((hi ^ key) << 4));
    bf16x8 pb11 = *(const bf16x8*)(rP1 + lq * 128 + (((4 + hi) ^ key) << 4));

    __builtin_amdgcn_s_setprio(1);
#pragma unroll
    for (int ft = 0; ft < 8; ++ft) {
      const unsigned short* vr = &sV[(fh * 128 + ft * 16 + lq) * 64];
      bf16x8 vf0 = *(const bf16x8*)(vr + ((hi ^ key) * 8));
      bf16x8 vf1 = *(const bf16x8*)(vr + (((4 + hi) ^ key) * 8));
      acc[0][ft] = MFMA16(vf0, pb00, acc[0][ft]);
      acc[0][ft] = MFMA16(vf1, pb01, acc[0][ft]);
      acc[1][ft] = MFMA16(vf0, pb10, acc[1][ft]);
      acc[1][ft] = MFMA16(vf1, pb11, acc[1][ft]);
    }
    __builtin_amdgcn_s_setprio(0);

    asm volatile("s_waitcnt lgkmcnt(0)" ::: "memory");
    __builtin_amdgcn_sched_barrier(0);
    __builtin_amdgcn_s_barrier();                       // bar3
  }

  // ---- epilogue: 1/l per group; store bf16 partials + (m,l) ----
  if (hi == 0) {
    sInv[wid][lq] = 1.0f / lrun;
    float* ml = (float*)(wsb + oMl);
    size_t qi = (size_t)(kvh * 8 + bm) * 3072 + q0 + wid * 16 + lq;
    *(float2*)(ml + qi * 2) = make_float2(mrun, lrun);
  }
  __syncthreads();

  unsigned short* paB = (unsigned short*)(wsb + oPa) + (size_t)(kvh * 8 + bm) * 3072 * 256;
#pragma unroll
  for (int gi = 0; gi < 2; ++gi) {
    int g = gp * 2 + gi;
    float inv = sInv[g][lq];
    unsigned short* orow = paB + (size_t)(q0 + g * 16 + lq) * 256 + fh * 128 + hi * 4;
#pragma unroll
    for (int ft = 0; ft < 8; ++ft) {
      u16x4 pk4;
#pragma unroll
      for (int r = 0; r < 4; ++r) pk4[r] = f2bf(acc[gi][ft][r] * inv);
      *(u16x4*)(orow + ft * 16) = pk4;
    }
  }
}

// ================= kernel 4: combine + FFN + LN + mode aggregation ===========
// grid 768 = 2 b x 384 u-blocks of 8. Rows: row = du*4 + m (32 rows).
__global__ __launch_bounds__(256, 3) void ffn_kernel(char* __restrict__ wsb,
                                                     const float* __restrict__ bmid,
                                                     const float* __restrict__ bout,
                                                     const float* __restrict__ lng,
                                                     const float* __restrict__ lnb,
                                                     const float* __restrict__ wagg,
                                                     const float* __restrict__ bagg,
                                                     float* __restrict__ out) {
  __shared__ unsigned short sA[32 * 256];   // 16KB combined fused bf16 (swizzled)
  __shared__ unsigned short sM[32 * 256];   // 16KB mid bf16 (swizzled)
  __shared__ float redS[4][32], redQ[4][32], redC[4][32];
  __shared__ float sSc[32];
  __shared__ float sW0[32], sW1[32];

  const int lane = threadIdx.x & 63, wid = threadIdx.x >> 6;
  const int lq = lane & 15, hi = lane >> 4;
  const int b = blockIdx.x / 384;
  const int u0 = (blockIdx.x % 384) * 8;

  const unsigned short* Wm = (const unsigned short*)(wsb + oWm);
  const unsigned short* Wo = (const unsigned short*)(wsb + oWo);
  const unsigned short* pa = (const unsigned short*)(wsb + oPa);
  const float* mlb = (const float*)(wsb + oMl);

  // ---- combine weights per row (row = du*4 + m) ----
  if (threadIdx.x < 32) {
    int m = threadIdx.x & 3, du = threadIdx.x >> 2;
    size_t qi = (size_t)(b * 4 + m) * 3072 + u0 + du;
    float2 ml0 = *(const float2*)(mlb + qi * 2);
    float2 ml1 = *(const float2*)(mlb + (qi + 8ull * 3072) * 2);
    float M = fmaxf(ml0.x, ml1.x);
    float e0 = ml0.y * __builtin_amdgcn_exp2f((ml0.x - M) * 1.44269504f);
    float e1 = ml1.y * __builtin_amdgcn_exp2f((ml1.x - M) * 1.44269504f);
    float inv = 1.0f / (e0 + e1);
    sW0[threadIdx.x] = e0 * inv;
    sW1[threadIdx.x] = e1 * inv;
  }
  __syncthreads();

  // ---- stage combined fused rows -> sA (bf16, swizzled) ----
  {
    int t = threadIdx.x;
#pragma unroll
    for (int j = 0; j < 4; ++j) {
      int i = j * 256 + t;             // over [32 rows][32 chunks]
      int row = i >> 5, c = i & 31;
      int m = row & 3, du = row >> 2;
      const unsigned short* p0 = pa + ((size_t)(b * 4 + m) * 3072 + u0 + du) * 256 + c * 8;
      bf16x8 a = *(const bf16x8*)(p0);
      bf16x8 bb = *(const bf16x8*)(p0 + 8ull * 3072 * 256);
      float w0 = sW0[row], w1 = sW1[row];
      u16x4 oA, oB;
#pragma unroll
      for (int e = 0; e < 4; ++e) {
        oA[e] = f2bf(w0 * bf2f((unsigned short)a[e]) + w1 * bf2f((unsigned short)bb[e]));
        oB[e] = f2bf(w0 * bf2f((unsigned short)a[e + 4]) + w1 * bf2f((unsigned short)bb[e + 4]));
      }
      unsigned short* dst = &sA[row * 256 + ((c ^ (row & 7)) << 3)];
      *(u16x4*)(dst) = oA;
      *(u16x4*)(dst + 4) = oB;
    }
  }
  __syncthreads();

  const int n0 = wid * 64;
  const int rowb = hi * 4;

  // ---- GEMM1: fused @ Wm^T (32 rows, this wave's 64 cols) ----
  f32x4 acc1[2][4];
#pragma unroll
  for (int rg = 0; rg < 2; ++rg)
#pragma unroll
    for (int bt = 0; bt < 4; ++bt) acc1[rg][bt] = (f32x4){0.f, 0.f, 0.f, 0.f};
#pragma unroll
  for (int ks = 0; ks < 8; ++ks) {
    bf16x8 a[2];
#pragma unroll
    for (int rg = 0; rg < 2; ++rg)
      a[rg] = *(const bf16x8*)&sA[(rg * 16 + lq) * 256 + (((ks * 4 + hi) ^ (lq & 7)) << 3)];
#pragma unroll
    for (int bt = 0; bt < 4; ++bt) {
      int n = n0 + bt * 16 + lq;
      bf16x8 bfr = *(const bf16x8*)(Wm + (size_t)n * 256 + ks * 32 + hi * 8);
#pragma unroll
      for (int rg = 0; rg < 2; ++rg) acc1[rg][bt] = MFMA16(a[rg], bfr, acc1[rg][bt]);
    }
  }
  // gelu (fast exact erf) -> sM
#pragma unroll
  for (int bt = 0; bt < 4; ++bt) {
    int n = n0 + bt * 16 + lq;
    float bb = bmid[n];
#pragma unroll
    for (int rg = 0; rg < 2; ++rg)
#pragma unroll
      for (int r = 0; r < 4; ++r) {
        float x = acc1[rg][bt][r] + bb;
        float g = 0.5f * x * (1.0f + fast_erf(x * 0.7071067811865475f));
        int row = rg * 16 + rowb + r;
        sM[row * 256 + (((n >> 3) ^ (row & 7)) << 3) + (n & 7)] = f2bf(g);
      }
  }
  __syncthreads();

  // ---- GEMM2: mid @ Wo^T ----
  f32x4 acc2[2][4];
#pragma unroll
  for (int rg = 0; rg < 2; ++rg)
#pragma unroll
    for (int bt = 0; bt < 4; ++bt) acc2[rg][bt] = (f32x4){0.f, 0.f, 0.f, 0.f};
#pragma unroll
  for (int ks = 0; ks < 8; ++ks) {
    bf16x8 a[2];
#pragma unroll
    for (int rg = 0; rg < 2; ++rg)
      a[rg] = *(const bf16x8*)&sM[(rg * 16 + lq) * 256 + (((ks * 4 + hi) ^ (lq & 7)) << 3)];
#pragma unroll
    for (int bt = 0; bt < 4; ++bt) {
      int n = n0 + bt * 16 + lq;
      bf16x8 bfr = *(const bf16x8*)(Wo + (size_t)n * 256 + ks * 32 + hi * 8);
#pragma unroll
      for (int rg = 0; rg < 2; ++rg) acc2[rg][bt] = MFMA16(a[rg], bfr, acc2[rg][bt]);
    }
  }

  // ---- + b_out + residual; LN partial sums ----
  float sS[2][4], sQ[2][4];
#pragma unroll
  for (int rg = 0; rg < 2; ++rg)
#pragma unroll
    for (int r = 0; r < 4; ++r) { sS[rg][r] = 0.f; sQ[rg][r] = 0.f; }
#pragma unroll
  for (int bt = 0; bt < 4; ++bt) {
    int n = n0 + bt * 16 + lq;
    float bo = bout[n];
#pragma unroll
    for (int rg = 0; rg < 2; ++rg)
#pragma unroll
      for (int r = 0; r < 4; ++r) {
        int row = rg * 16 + rowb + r;
        float res = bf2f(sA[row * 256 + (((n >> 3) ^ (row & 7)) << 3) + (n & 7)]);
        float x = acc2[rg][bt][r] + bo + res;
        acc2[rg][bt][r] = x;
        sS[rg][r] += x;
        sQ[rg][r] += x * x;
      }
  }
#pragma unroll
  for (int rg = 0; rg < 2; ++rg)
#pragma unroll
    for (int r = 0; r < 4; ++r) {
#pragma unroll
      for (int off = 1; off < 16; off <<= 1) {
        sS[rg][r] += __shfl_xor(sS[rg][r], off);
        sQ[rg][r] += __shfl_xor(sQ[rg][r], off);
      }
    }
  if (lq == 0) {
#pragma unroll
    for (int rg = 0; rg < 2; ++rg)
#pragma unroll
      for (int r = 0; r < 4; ++r) {
        int row = rg * 16 + rowb + r;
        redS[wid][row] = sS[rg][r]; redQ[wid][row] = sQ[rg][r];
      }
  }
  __syncthreads();

  // ---- LN transform (in-place into acc2) + agg score partials ----
  float scp[2][4];
#pragma unroll
  for (int rg = 0; rg < 2; ++rg)
#pragma unroll
    for (int r = 0; r < 4; ++r) {
      int row = rg * 16 + rowb + r;
      float ts = redS[0][row] + redS[1][row] + redS[2][row] + redS[3][row];
      float tq = redQ[0][row] + redQ[1][row] + redQ[2][row] + redQ[3][row];
      float mean = ts * (1.0f / 256.0f);
      float var = tq * (1.0f / 256.0f) - mean * mean;
      float rs = rsqrtf(var + 1e-12f);
      float sc = 0.f;
#pragma unroll
      for (int bt = 0; bt < 4; ++bt) {
        int n = n0 + bt * 16 + lq;
        float o = (acc2[rg][bt][r] - mean) * rs * lng[n] + lnb[n];
        acc2[rg][bt][r] = o;
        sc += o * wagg[n];
      }
      scp[rg][r] = sc;
    }
#pragma unroll
  for (int rg = 0; rg < 2; ++rg)
#pragma unroll
    for (int r = 0; r < 4; ++r) {
#pragma unroll
      for (int off = 1; off < 16; off <<= 1) scp[rg][r] += __shfl_xor(scp[rg][r], off);
    }
  if (lq == 0) {
#pragma unroll
    for (int rg = 0; rg < 2; ++rg)
#pragma unroll
      for (int r = 0; r < 4; ++r) redC[wid][rg * 16 + rowb + r] = scp[rg][r];
  }
  __syncthreads();

  if (threadIdx.x < 32) {
    int t = threadIdx.x;
    sSc[t] = redC[0][t] + redC[1][t] + redC[2][t] + redC[3][t] + bagg[0];
  }
  __syncthreads();

  // ---- mode softmax + weighted sum (modes are the 4 regs r of acc2[rg]) ----
  float wm[2][4];   // [rg][m], du = rg*4 + hi
#pragma unroll
  for (int rg = 0; rg < 2; ++rg) {
    int du = rg * 4 + hi;
    float s0 = sSc[du * 4 + 0], s1 = sSc[du * 4 + 1];
    float s2 = sSc[du * 4 + 2], s3 = sSc[du * 4 + 3];
    float mx = fmaxf(fmaxf(s0, s1), fmaxf(s2, s3));
    float e0 = __builtin_amdgcn_exp2f((s0 - mx) * 1.44269504f);
    float e1 = __builtin_amdgcn_exp2f((s1 - mx) * 1.44269504f);
    float e2 = __builtin_amdgcn_exp2f((s2 - mx) * 1.44269504f);
    float e3 = __builtin_amdgcn_exp2f((s3 - mx) * 1.44269504f);
    float inv = 1.0f / (e0 + e1 + e2 + e3);
    wm[rg][0] = e0 * inv; wm[rg][1] = e1 * inv;
    wm[rg][2] = e2 * inv; wm[rg][3] = e3 * inv;
  }
#pragma unroll
  for (int bt = 0; bt < 4; ++bt) {
    int n = n0 + bt * 16 + lq;
#pragma unroll
    for (int rg = 0; rg < 2; ++rg) {
      int du = rg * 4 + hi;
      float val = wm[rg][0] * acc2[rg][bt][0] + wm[rg][1] * acc2[rg][bt][1]
                + wm[rg][2] * acc2[rg][bt][2] + wm[rg][3] * acc2[rg][bt][3];
      out[((size_t)(b * 3072 + u0 + du)) * 256 + n] = val;
    }
  }
}

// ================= launcher =================
extern "C" void kernel_launch(void* const* d_in, const int* in_sizes, int n_in,
                              void* d_out, int out_size, void* d_ws, size_t ws_size,
                              hipStream_t stream) {
  const float* q  = (const float*)d_in[0];
  const float* k  = (const float*)d_in[1];
  const float* wq = (const float*)d_in[2];
  const float* wv = (const float*)d_in[3];
  const float* bv = (const float*)d_in[4];
  const float* wm = (const float*)d_in[5];
  const float* bm = (const float*)d_in[6];
  const float* wo = (const float*)d_in[7];
  const float* bo = (const float*)d_in[8];
  const float* lg = (const float*)d_in[9];
  const float* lb = (const float*)d_in[10];
  const float* wa = (const float*)d_in[11];
  const float* ba = (const float*)d_in[12];
  char* wsb = (char*)d_ws;

  cvtw_kernel<<<448, 256, 0, stream>>>(wq, wv, wm, wo, wsb);
  proj_kernel<<<576, 256, 0, stream>>>(q, k, bv, wsb);
  attn_kernel<<<768, 256, 0, stream>>>(wsb);
  ffn_kernel<<<768, 256, 0, stream>>>(wsb, bm, bo, lg, lb, wa, ba, (float*)d_out);
}

// Round 11
// 127.045 us; speedup vs baseline: 1.4013x; 1.0101x over previous
//
#include <hip/hip_runtime.h>
#include <hip/hip_bf16.h>
#include <cstdint>
#include <cstddef>

// ---------------- types ----------------
typedef __attribute__((ext_vector_type(8))) short     bf16x8;
typedef __attribute__((ext_vector_type(4))) float     f32x4;
typedef __attribute__((ext_vector_type(4))) unsigned short u16x4;

using as1_void = __attribute__((address_space(1))) void;
using as3_void = __attribute__((address_space(3))) void;

#define MFMA16(a,b,c) __builtin_amdgcn_mfma_f32_16x16x32_bf16((a),(b),(c),0,0,0)

__device__ __forceinline__ unsigned short f2bf(float f) {
  union { float f; unsigned u; } v; v.f = f;
  unsigned r = v.u + 0x7fffu + ((v.u >> 16) & 1u);
  return (unsigned short)(r >> 16);
}
__device__ __forceinline__ float bf2f(unsigned short h) {
  union { unsigned u; float f; } v; v.u = ((unsigned)h) << 16; return v.f;
}
__device__ __forceinline__ unsigned cvt_pk_bf16(float lo, float hi) {
  unsigned r;
  asm volatile("v_cvt_pk_bf16_f32 %0, %1, %2" : "=v"(r) : "v"(lo), "v"(hi));
  return r;
}
// A&S 7.1.26 minimax erf, |err| <= 1.5e-7 (exact at bf16 scale)
__device__ __forceinline__ float fast_erf(float x) {
  float ax = fabsf(x);
  float t = __builtin_amdgcn_rcpf(fmaf(0.3275911f, ax, 1.0f));
  float p = fmaf(1.061405429f, t, -1.453152027f);
  p = fmaf(p, t, 1.421413741f);
  p = fmaf(p, t, -0.284496736f);
  p = fmaf(p, t, 0.254829592f);
  p = p * t;
  float e = __builtin_amdgcn_exp2f(-ax * ax * 1.44269504f);
  float r = fmaf(-p, e, 1.0f);
  return copysignf(r, x);
}

__device__ __forceinline__ void gload16(const void* g, void* l) {
  __builtin_amdgcn_global_load_lds((const as1_void*)g, (as3_void*)l, 16, 0, 0);
}

// ---------------- problem constants ----------------
// B=2, U1=U2=3072, IF=256, FD=256, M=4, D=64
constexpr size_t oXq  = 0;                       // (unused)
constexpr size_t oXk  = oXq + 1572864ull * 2;    // (unused)
constexpr size_t oWq  = oXk + 1572864ull * 2;    // bf16 [256*256]
constexpr size_t oWv  = oWq + 65536ull   * 2;    // bf16 [1024*256]
constexpr size_t oWm  = oWv + 262144ull  * 2;    // bf16 [256*256]
constexpr size_t oWo  = oWm + 65536ull   * 2;    // bf16 [256*256]
constexpr size_t oQb  = oWo + 65536ull   * 2;    // bf16 [8][3072][64]  (q/8)
constexpr size_t oKb  = oQb + 1572864ull * 2;    // bf16 [8][3072][64]
constexpr size_t oVb  = oKb + 1572864ull * 2;    // bf16 [8][256][3072] (V^T)
constexpr size_t oPa  = oVb + 6291456ull * 2;    // bf16 [2][8][3072][256] O partials
constexpr size_t oMl  = oPa + 12582912ull * 2;   // f32  [2][8][3072][2]  (m,l)

// ================= kernel 1: f32 -> bf16 conversion (weights only) ===========
__global__ __launch_bounds__(256) void cvtw_kernel(
    const float* __restrict__ wq, const float* __restrict__ wv,
    const float* __restrict__ wm, const float* __restrict__ wo,
    char* __restrict__ wsb) {
  int i4 = (blockIdx.x * 256 + threadIdx.x) * 4;   // over 458752 elems
  const float* src; size_t dsto; int local;
  if (i4 < 65536)        { src = wq; dsto = oWq; local = i4; }
  else if (i4 < 327680)  { src = wv; dsto = oWv; local = i4 - 65536; }
  else if (i4 < 393216)  { src = wm; dsto = oWm; local = i4 - 327680; }
  else                   { src = wo; dsto = oWo; local = i4 - 393216; }
  f32x4 v = *(const f32x4*)(src + local);
  u16x4 o;
  o.x = f2bf(v.x); o.y = f2bf(v.y); o.z = f2bf(v.z); o.w = f2bf(v.w);
  *(u16x4*)((unsigned short*)(wsb + dsto) + local) = o;
}

// ================= kernel 2: projections q,k,v (48-row blocks, 3.0/CU) =======
// grid 768 = 128 rowblocks x 6 ny. ny=0: q=Xq@Wq^T*0.125; ny=1: k=Xk@Wq^T;
// ny=2..5: v chunk = Xk@Wv^T + bv (transposed store).
__global__ __launch_bounds__(256, 3) void proj_kernel(
    const float* __restrict__ qf32, const float* __restrict__ kf32,
    const float* __restrict__ bv, char* __restrict__ wsb) {
  __shared__ unsigned short sA[48 * 256];   // 24KB bf16 (chunk-swizzled)

  const int lane = threadIdx.x & 63, wid = threadIdx.x >> 6;
  const int lq = lane & 15, hi = lane >> 4;
  const int ny = blockIdx.x % 6;
  const int r0 = (blockIdx.x / 6) * 48;

  const float* Xf = (ny == 0) ? qf32 : kf32;
  const unsigned short* W;
  if (ny <= 1) W = (const unsigned short*)(wsb + oWq);
  else         W = (const unsigned short*)(wsb + oWv) + (size_t)(ny - 2) * 256 * 256;

  // ---- stage A: 48 rows f32 -> bf16 LDS (coalesced, swizzled) ----
  {
    const int t = threadIdx.x;
#pragma unroll
    for (int j = 0; j < 12; ++j) {
      int flat = j * 256 + t;            // f32x4 units over [48][64]
      int row = flat >> 6;
      int c4 = flat & 63;
      f32x4 v = *(const f32x4*)(Xf + ((size_t)(r0 + row) * 256 + c4 * 4));
      u16x4 o;
      o.x = f2bf(v.x); o.y = f2bf(v.y); o.z = f2bf(v.z); o.w = f2bf(v.w);
      int col = c4 * 4;
      int c8 = col >> 3;
      *(u16x4*)&sA[row * 256 + (((c8 ^ (row & 7)) << 3) + (col & 7))] = o;
    }
  }
  __syncthreads();

  const int n0 = wid * 64;

  // ---- GEMM: 48 rows x this wave's 64 cols, K=256 ----
  f32x4 acc[3][4];   // [rg][bt]
#pragma unroll
  for (int rg = 0; rg < 3; ++rg)
#pragma unroll
    for (int bt = 0; bt < 4; ++bt) acc[rg][bt] = (f32x4){0.f, 0.f, 0.f, 0.f};

#pragma unroll
  for (int ks = 0; ks < 8; ++ks) {
    bf16x8 a[3];
#pragma unroll
    for (int rg = 0; rg < 3; ++rg)
      a[rg] = *(const bf16x8*)&sA[(rg * 16 + lq) * 256 + (((ks * 4 + hi) ^ (lq & 7)) << 3)];
#pragma unroll
    for (int bt = 0; bt < 4; ++bt) {
      int n = n0 + bt * 16 + lq;
      bf16x8 bfr = *(const bf16x8*)(W + (size_t)n * 256 + ks * 32 + hi * 8);
#pragma unroll
      for (int rg = 0; rg < 3; ++rg) acc[rg][bt] = MFMA16(a[rg], bfr, acc[rg][bt]);
    }
  }

  const int b = r0 / 3072, u0 = r0 % 3072;

  if (ny <= 1) {
    unsigned short* outp = (unsigned short*)(wsb + (ny == 0 ? oQb : oKb));
    float scale = (ny == 0) ? 0.125f : 1.0f;
    int m = wid;
#pragma unroll
    for (int bt = 0; bt < 4; ++bt) {
      int d = bt * 16 + lq;
#pragma unroll
      for (int rg = 0; rg < 3; ++rg) {
        int ub = u0 + rg * 16 + hi * 4;
#pragma unroll
        for (int r = 0; r < 4; ++r) {
          outp[((size_t)(b * 4 + m) * 3072 + (ub + r)) * 64 + d] = f2bf(acc[rg][bt][r] * scale);
        }
      }
    }
  } else {
    unsigned short* vbT = (unsigned short*)(wsb + oVb);
    int mchunk = ny - 2;
#pragma unroll
    for (int bt = 0; bt < 4; ++bt) {
      int f = n0 + bt * 16 + lq;
      float bias = bv[mchunk * 256 + f];
#pragma unroll
      for (int rg = 0; rg < 3; ++rg) {
        int ub = u0 + rg * 16 + hi * 4;
        u16x4 pk;
#pragma unroll
        for (int r = 0; r < 4; ++r) pk[r] = f2bf(acc[rg][bt][r] + bias);
        *(u16x4*)(vbT + ((size_t)(b * 4 + mchunk) * 256 + f) * 3072 + ub) = pk;
      }
    }
  }
}

// ================= kernel 3: flash attention (R7 schedule + hoisted addrs) ===
// grid 768 x 256 (4 waves): bm = bid&7 (XCD pin), z = bid>>3: qt = z>>1 (64 q),
// kvh = z&1 (kv half, 24 tiles of 64).
// IDENTICAL barrier schedule to the proven 73us kernel:
//   issue V(8) -> vmcnt(8) bar1 -> QK/SM/pack -> vmcnt(0)+lgkm bar2
//   -> issue K(t+1) -> rescale+PV -> lgkm bar3.
// Only change: all swizzled LDS addresses hoisted to loop-invariant registers.
__global__ __launch_bounds__(256, 3) void attn_kernel(char* __restrict__ wsb) {
  __shared__ unsigned short sK[64 * 64];        // 8KB  [kv][d]  chunk-swizzled
  __shared__ unsigned short sV[256 * 64];       // 32KB [f][kv]  chunk-swizzled
  __shared__ unsigned short sP[4][16 * 64];     // 8KB  [g]      P^T
  __shared__ float sCr[4];
  __shared__ float sInv[4][16];

  const int lane = threadIdx.x & 63, wid = threadIdx.x >> 6;
  const int lq = lane & 15, hi = lane >> 4;
  const int lr3 = lane >> 3, lc3 = lane & 7;
  const int fh = wid >> 1, gp = wid & 1;
  const int bm = blockIdx.x & 7;
  const int z = blockIdx.x >> 3;
  const int qt = z >> 1, kvh = z & 1;
  const int q0 = qt * 64;
  const int kvbase = kvh * 1536;
  const int key = lq & 7;

  const unsigned short* qb = (const unsigned short*)(wsb + oQb) + (size_t)bm * 3072 * 64;
  const unsigned short* kb = (const unsigned short*)(wsb + oKb) + (size_t)bm * 3072 * 64;
  const unsigned short* vb = (const unsigned short*)(wsb + oVb) + (size_t)bm * 256 * 3072;

  // persistent Q B-frags for this wave's group (q = q0 + wid*16 + lq)
  const unsigned short* qp = qb + (size_t)(q0 + wid * 16 + lq) * 64 + hi * 8;
  const bf16x8 qf0 = *(const bf16x8*)(qp);
  const bf16x8 qf1 = *(const bf16x8*)(qp + 32);
  asm volatile("s_waitcnt vmcnt(0)" ::: "memory");   // qf resident; vmcnt clean

  // staging pointers (bumped per tile)
  const unsigned short* pk[2];
  unsigned short* dk[2];
#pragma unroll
  for (int i = 0; i < 2; ++i) {
    int ch = wid * 2 + i;
    int r = ch * 8 + lr3;
    int cs = lc3 ^ (r & 7);
    pk[i] = kb + (size_t)(kvbase + r) * 64 + cs * 8;
    dk[i] = &sK[ch * 512];
  }
  const unsigned short* pv[8];
  unsigned short* dv[8];
#pragma unroll
  for (int i = 0; i < 8; ++i) {
    int ch = i * 4 + wid;
    int f = ch * 8 + lr3;
    int cs = lc3 ^ (f & 7);
    pv[i] = vb + (size_t)f * 3072 + kvbase + cs * 8;
    dv[i] = &sV[ch * 512];
  }

  // hoisted loop-invariant LDS addresses
  const int o0 = (hi ^ key) << 4;            // byte offset of k-slice 0
  const int o1 = ((hi + 4) ^ key) << 4;      // byte offset of k-slice 1
  const char* kB0 = (const char*)sK + lq * 128 + o0;
  const char* kB1 = (const char*)sK + lq * 128 + o1;
  const char* vB0 = (const char*)sV + (size_t)(fh * 128 + lq) * 128 + o0;
  const char* vB1 = (const char*)sV + (size_t)(fh * 128 + lq) * 128 + o1;
  char* myP = (char*)&sP[wid][0] + lq * 128;
  int wofs[4];
#pragma unroll
  for (int t = 0; t < 4; ++t)
    wofs[t] = ((((2 * t + (hi >> 1)) ^ key) << 4) + ((hi & 1) << 3));
  const int g0 = gp * 2, g1 = gp * 2 + 1;
  const char* rP0 = (const char*)&sP[g0][0] + lq * 128;
  const char* rP1 = (const char*)&sP[g1][0] + lq * 128;

  f32x4 acc[2][8];
#pragma unroll
  for (int g = 0; g < 2; ++g)
#pragma unroll
    for (int ft = 0; ft < 8; ++ft) acc[g][ft] = (f32x4){0.f, 0.f, 0.f, 0.f};
  float mrun = -1e30f, lrun = 0.f;

  // prologue: issue K tile 0
  gload16(pk[0], dk[0]); gload16(pk[1], dk[1]);
  pk[0] += 4096; pk[1] += 4096;

  for (int kt = 0; kt < 24; ++kt) {
    // ---- issue V tile kt (8 chunks this wave) ----
#pragma unroll
    for (int i = 0; i < 8; ++i) { gload16(pv[i], dv[i]); pv[i] += 64; }

    asm volatile("s_waitcnt vmcnt(8)" ::: "memory");   // K landed (V in flight)
    __builtin_amdgcn_sched_barrier(0);
    __builtin_amdgcn_s_barrier();                       // bar1

    // ---- QK^T group w: s[t][r] = S[q=lq][t*16 + hi*4 + r] ----
    bf16x8 kc0[4], kc1[4];
#pragma unroll
    for (int t = 0; t < 4; ++t) {
      kc0[t] = *(const bf16x8*)(kB0 + t * 2048);
      kc1[t] = *(const bf16x8*)(kB1 + t * 2048);
    }
    f32x4 s[4];
#pragma unroll
    for (int t = 0; t < 4; ++t) {
      f32x4 zz = (f32x4){0.f, 0.f, 0.f, 0.f};
      zz = MFMA16(kc0[t], qf0, zz);
      zz = MFMA16(kc1[t], qf1, zz);
      s[t] = zz;
    }

    // ---- lane-local online softmax ----
    float pmax = s[0][0];
#pragma unroll
    for (int t = 0; t < 4; ++t)
#pragma unroll
      for (int r = 0; r < 4; ++r) pmax = fmaxf(pmax, s[t][r]);
    pmax = fmaxf(pmax, __shfl_xor(pmax, 16));
    pmax = fmaxf(pmax, __shfl_xor(pmax, 32));

    float cr = 1.0f;
    if (__any(pmax > mrun + 8.0f)) {        // defer-max
      float mnew = fmaxf(mrun, pmax);
      cr = __builtin_amdgcn_exp2f((mrun - mnew) * 1.44269504f);
      lrun *= cr; mrun = mnew;
    }
    if (lane == 0) sCr[wid] = cr;

    const float mk = mrun * 1.44269504f;
    float ps[4][4];
    float psum = 0.f;
#pragma unroll
    for (int t = 0; t < 4; ++t)
#pragma unroll
      for (int r = 0; r < 4; ++r) {
        float p = __builtin_amdgcn_exp2f(s[t][r] * 1.44269504f - mk);
        ps[t][r] = p; psum += p;
      }
    psum += __shfl_xor(psum, 16);
    psum += __shfl_xor(psum, 32);
    lrun += psum;

    // ---- pack P^T -> sP[w] (cvt_pk, hoisted offsets) ----
#pragma unroll
    for (int t = 0; t < 4; ++t) {
      unsigned w0 = cvt_pk_bf16(ps[t][0], ps[t][1]);
      unsigned w1 = cvt_pk_bf16(ps[t][2], ps[t][3]);
      *(uint2*)(myP + wofs[t]) = make_uint2(w0, w1);
    }

    asm volatile("s_waitcnt vmcnt(0) lgkmcnt(0)" ::: "memory");  // V + P ready
    __builtin_amdgcn_sched_barrier(0);
    __builtin_amdgcn_s_barrier();                       // bar2

    // ---- issue K tile kt+1 (latency hides under PV) ----
    if (kt < 23) {
      gload16(pk[0], dk[0]); gload16(pk[1], dk[1]);
      pk[0] += 4096; pk[1] += 4096;
    }

    // ---- rescale (cross-wave factors) ----
    float c0 = sCr[g0], c1 = sCr[g1];
    if (c0 != 1.0f) {
#pragma unroll
      for (int ft = 0; ft < 8; ++ft) {
        acc[0][ft][0] *= c0; acc[0][ft][1] *= c0;
        acc[0][ft][2] *= c0; acc[0][ft][3] *= c0;
      }
    }
    if (c1 != 1.0f) {
#pragma unroll
      for (int ft = 0; ft < 8; ++ft) {
        acc[1][ft][0] *= c1; acc[1][ft][1] *= c1;
        acc[1][ft][2] *= c1; acc[1][ft][3] *= c1;
      }
    }

    // ---- PV on f-half fh for groups g0,g1 (hoisted bases) ----
    bf16x8 pb00 = *(const bf16x8*)(rP0 + o0);
    bf16x8 pb01 = *(const bf16x8*)(rP0 + o1);
    bf16x8 pb10 = *(const bf16x8*)(rP1 + o0);
    bf16x8 pb11 = *(const bf16x8*)(rP1 + o1);

    __builtin_amdgcn_s_setprio(1);
#pragma unroll
    for (int ft = 0; ft < 8; ++ft) {
      bf16x8 vf0 = *(const bf16x8*)(vB0 + ft * 2048);
      bf16x8 vf1 = *(const bf16x8*)(vB1 + ft * 2048);
      acc[0][ft] = MFMA16(vf0, pb00, acc[0][ft]);
      acc[0][ft] = MFMA16(vf1, pb01, acc[0][ft]);
      acc[1][ft] = MFMA16(vf0, pb10, acc[1][ft]);
      acc[1][ft] = MFMA16(vf1, pb11, acc[1][ft]);
    }
    __builtin_amdgcn_s_setprio(0);

    asm volatile("s_waitcnt lgkmcnt(0)" ::: "memory");
    __builtin_amdgcn_sched_barrier(0);
    __builtin_amdgcn_s_barrier();                       // bar3
  }

  // ---- epilogue: 1/l per group; store bf16 partials + (m,l) ----
  if (hi == 0) {
    sInv[wid][lq] = 1.0f / lrun;
    float* ml = (float*)(wsb + oMl);
    size_t qi = (size_t)(kvh * 8 + bm) * 3072 + q0 + wid * 16 + lq;
    *(float2*)(ml + qi * 2) = make_float2(mrun, lrun);
  }
  __syncthreads();

  unsigned short* paB = (unsigned short*)(wsb + oPa) + (size_t)(kvh * 8 + bm) * 3072 * 256;
#pragma unroll
  for (int gi = 0; gi < 2; ++gi) {
    int g = gp * 2 + gi;
    float inv = sInv[g][lq];
    unsigned short* orow = paB + (size_t)(q0 + g * 16 + lq) * 256 + fh * 128 + hi * 4;
#pragma unroll
    for (int ft = 0; ft < 8; ++ft) {
      u16x4 pk4;
#pragma unroll
      for (int r = 0; r < 4; ++r) pk4[r] = f2bf(acc[gi][ft][r] * inv);
      *(u16x4*)(orow + ft * 16) = pk4;
    }
  }
}

// ================= kernel 4: combine + FFN + LN + mode aggregation ===========
// grid 768 = 2 b x 384 u-blocks of 8. Rows: row = du*4 + m (32 rows).
__global__ __launch_bounds__(256, 3) void ffn_kernel(char* __restrict__ wsb,
                                                     const float* __restrict__ bmid,
                                                     const float* __restrict__ bout,
                                                     const float* __restrict__ lng,
                                                     const float* __restrict__ lnb,
                                                     const float* __restrict__ wagg,
                                                     const float* __restrict__ bagg,
                                                     float* __restrict__ out) {
  __shared__ unsigned short sA[32 * 256];   // 16KB combined fused bf16 (swizzled)
  __shared__ unsigned short sM[32 * 256];   // 16KB mid bf16 (swizzled)
  __shared__ float redS[4][32], redQ[4][32], redC[4][32];
  __shared__ float sSc[32];
  __shared__ float sW0[32], sW1[32];

  const int lane = threadIdx.x & 63, wid = threadIdx.x >> 6;
  const int lq = lane & 15, hi = lane >> 4;
  const int b = blockIdx.x / 384;
  const int u0 = (blockIdx.x % 384) * 8;

  const unsigned short* Wm = (const unsigned short*)(wsb + oWm);
  const unsigned short* Wo = (const unsigned short*)(wsb + oWo);
  const unsigned short* pa = (const unsigned short*)(wsb + oPa);
  const float* mlb = (const float*)(wsb + oMl);

  // ---- combine weights per row (row = du*4 + m) ----
  if (threadIdx.x < 32) {
    int m = threadIdx.x & 3, du = threadIdx.x >> 2;
    size_t qi = (size_t)(b * 4 + m) * 3072 + u0 + du;
    float2 ml0 = *(const float2*)(mlb + qi * 2);
    float2 ml1 = *(const float2*)(mlb + (qi + 8ull * 3072) * 2);
    float M = fmaxf(ml0.x, ml1.x);
    float e0 = ml0.y * __builtin_amdgcn_exp2f((ml0.x - M) * 1.44269504f);
    float e1 = ml1.y * __builtin_amdgcn_exp2f((ml1.x - M) * 1.44269504f);
    float inv = 1.0f / (e0 + e1);
    sW0[threadIdx.x] = e0 * inv;
    sW1[threadIdx.x] = e1 * inv;
  }
  __syncthreads();

  // ---- stage combined fused rows -> sA (bf16, swizzled) ----
  {
    int t = threadIdx.x;
#pragma unroll
    for (int j = 0; j < 4; ++j) {
      int i = j * 256 + t;             // over [32 rows][32 chunks]
      int row = i >> 5, c = i & 31;
      int m = row & 3, du = row >> 2;
      const unsigned short* p0 = pa + ((size_t)(b * 4 + m) * 3072 + u0 + du) * 256 + c * 8;
      bf16x8 a = *(const bf16x8*)(p0);
      bf16x8 bb = *(const bf16x8*)(p0 + 8ull * 3072 * 256);
      float w0 = sW0[row], w1 = sW1[row];
      u16x4 oA, oB;
#pragma unroll
      for (int e = 0; e < 4; ++e) {
        oA[e] = f2bf(w0 * bf2f((unsigned short)a[e]) + w1 * bf2f((unsigned short)bb[e]));
        oB[e] = f2bf(w0 * bf2f((unsigned short)a[e + 4]) + w1 * bf2f((unsigned short)bb[e + 4]));
      }
      unsigned short* dst = &sA[row * 256 + ((c ^ (row & 7)) << 3)];
      *(u16x4*)(dst) = oA;
      *(u16x4*)(dst + 4) = oB;
    }
  }
  __syncthreads();

  const int n0 = wid * 64;
  const int rowb = hi * 4;

  // ---- GEMM1: fused @ Wm^T (32 rows, this wave's 64 cols) ----
  f32x4 acc1[2][4];
#pragma unroll
  for (int rg = 0; rg < 2; ++rg)
#pragma unroll
    for (int bt = 0; bt < 4; ++bt) acc1[rg][bt] = (f32x4){0.f, 0.f, 0.f, 0.f};
#pragma unroll
  for (int ks = 0; ks < 8; ++ks) {
    bf16x8 a[2];
#pragma unroll
    for (int rg = 0; rg < 2; ++rg)
      a[rg] = *(const bf16x8*)&sA[(rg * 16 + lq) * 256 + (((ks * 4 + hi) ^ (lq & 7)) << 3)];
#pragma unroll
    for (int bt = 0; bt < 4; ++bt) {
      int n = n0 + bt * 16 + lq;
      bf16x8 bfr = *(const bf16x8*)(Wm + (size_t)n * 256 + ks * 32 + hi * 8);
#pragma unroll
      for (int rg = 0; rg < 2; ++rg) acc1[rg][bt] = MFMA16(a[rg], bfr, acc1[rg][bt]);
    }
  }
  // gelu (fast exact erf) -> sM
#pragma unroll
  for (int bt = 0; bt < 4; ++bt) {
    int n = n0 + bt * 16 + lq;
    float bb = bmid[n];
#pragma unroll
    for (int rg = 0; rg < 2; ++rg)
#pragma unroll
      for (int r = 0; r < 4; ++r) {
        float x = acc1[rg][bt][r] + bb;
        float g = 0.5f * x * (1.0f + fast_erf(x * 0.7071067811865475f));
        int row = rg * 16 + rowb + r;
        sM[row * 256 + (((n >> 3) ^ (row & 7)) << 3) + (n & 7)] = f2bf(g);
      }
  }
  __syncthreads();

  // ---- GEMM2: mid @ Wo^T ----
  f32x4 acc2[2][4];
#pragma unroll
  for (int rg = 0; rg < 2; ++rg)
#pragma unroll
    for (int bt = 0; bt < 4; ++bt) acc2[rg][bt] = (f32x4){0.f, 0.f, 0.f, 0.f};
#pragma unroll
  for (int ks = 0; ks < 8; ++ks) {
    bf16x8 a[2];
#pragma unroll
    for (int rg = 0; rg < 2; ++rg)
      a[rg] = *(const bf16x8*)&sM[(rg * 16 + lq) * 256 + (((ks * 4 + hi) ^ (lq & 7)) << 3)];
#pragma unroll
    for (int bt = 0; bt < 4; ++bt) {
      int n = n0 + bt * 16 + lq;
      bf16x8 bfr = *(const bf16x8*)(Wo + (size_t)n * 256 + ks * 32 + hi * 8);
#pragma unroll
      for (int rg = 0; rg < 2; ++rg) acc2[rg][bt] = MFMA16(a[rg], bfr, acc2[rg][bt]);
    }
  }

  // ---- + b_out + residual; LN partial sums ----
  float sS[2][4], sQ[2][4];
#pragma unroll
  for (int rg = 0; rg < 2; ++rg)
#pragma unroll
    for (int r = 0; r < 4; ++r) { sS[rg][r] = 0.f; sQ[rg][r] = 0.f; }
#pragma unroll
  for (int bt = 0; bt < 4; ++bt) {
    int n = n0 + bt * 16 + lq;
    float bo = bout[n];
#pragma unroll
    for (int rg = 0; rg < 2; ++rg)
#pragma unroll
      for (int r = 0; r < 4; ++r) {
        int row = rg * 16 + rowb + r;
        float res = bf2f(sA[row * 256 + (((n >> 3) ^ (row & 7)) << 3) + (n & 7)]);
        float x = acc2[rg][bt][r] + bo + res;
        acc2[rg][bt][r] = x;
        sS[rg][r] += x;
        sQ[rg][r] += x * x;
      }
  }
#pragma unroll
  for (int rg = 0; rg < 2; ++rg)
#pragma unroll
    for (int r = 0; r < 4; ++r) {
#pragma unroll
      for (int off = 1; off < 16; off <<= 1) {
        sS[rg][r] += __shfl_xor(sS[rg][r], off);
        sQ[rg][r] += __shfl_xor(sQ[rg][r], off);
      }
    }
  if (lq == 0) {
#pragma unroll
    for (int rg = 0; rg < 2; ++rg)
#pragma unroll
      for (int r = 0; r < 4; ++r) {
        int row = rg * 16 + rowb + r;
        redS[wid][row] = sS[rg][r]; redQ[wid][row] = sQ[rg][r];
      }
  }
  __syncthreads();

  // ---- LN transform (in-place into acc2) + agg score partials ----
  float scp[2][4];
#pragma unroll
  for (int rg = 0; rg < 2; ++rg)
#pragma unroll
    for (int r = 0; r < 4; ++r) {
      int row = rg * 16 + rowb + r;
      float ts = redS[0][row] + redS[1][row] + redS[2][row] + redS[3][row];
      float tq = redQ[0][row] + redQ[1][row] + redQ[2][row] + redQ[3][row];
      float mean = ts * (1.0f / 256.0f);
      float var = tq * (1.0f / 256.0f) - mean * mean;
      float rs = rsqrtf(var + 1e-12f);
      float sc = 0.f;
#pragma unroll
      for (int bt = 0; bt < 4; ++bt) {
        int n = n0 + bt * 16 + lq;
        float o = (acc2[rg][bt][r] - mean) * rs * lng[n] + lnb[n];
        acc2[rg][bt][r] = o;
        sc += o * wagg[n];
      }
      scp[rg][r] = sc;
    }
#pragma unroll
  for (int rg = 0; rg < 2; ++rg)
#pragma unroll
    for (int r = 0; r < 4; ++r) {
#pragma unroll
      for (int off = 1; off < 16; off <<= 1) scp[rg][r] += __shfl_xor(scp[rg][r], off);
    }
  if (lq == 0) {
#pragma unroll
    for (int rg = 0; rg < 2; ++rg)
#pragma unroll
      for (int r = 0; r < 4; ++r) redC[wid][rg * 16 + rowb + r] = scp[rg][r];
  }
  __syncthreads();

  if (threadIdx.x < 32) {
    int t = threadIdx.x;
    sSc[t] = redC[0][t] + redC[1][t] + redC[2][t] + redC[3][t] + bagg[0];
  }
  __syncthreads();

  // ---- mode softmax + weighted sum (modes are the 4 regs r of acc2[rg]) ----
  float wm[2][4];   // [rg][m], du = rg*4 + hi
#pragma unroll
  for (int rg = 0; rg < 2; ++rg) {
    int du = rg * 4 + hi;
    float s0 = sSc[du * 4 + 0], s1 = sSc[du * 4 + 1];
    float s2 = sSc[du * 4 + 2], s3 = sSc[du * 4 + 3];
    float mx = fmaxf(fmaxf(s0, s1), fmaxf(s2, s3));
    float e0 = __builtin_amdgcn_exp2f((s0 - mx) * 1.44269504f);
    float e1 = __builtin_amdgcn_exp2f((s1 - mx) * 1.44269504f);
    float e2 = __builtin_amdgcn_exp2f((s2 - mx) * 1.44269504f);
    float e3 = __builtin_amdgcn_exp2f((s3 - mx) * 1.44269504f);
    float inv = 1.0f / (e0 + e1 + e2 + e3);
    wm[rg][0] = e0 * inv; wm[rg][1] = e1 * inv;
    wm[rg][2] = e2 * inv; wm[rg][3] = e3 * inv;
  }
#pragma unroll
  for (int bt = 0; bt < 4; ++bt) {
    int n = n0 + bt * 16 + lq;
#pragma unroll
    for (int rg = 0; rg < 2; ++rg) {
      int du = rg * 4 + hi;
      float val = wm[rg][0] * acc2[rg][bt][0] + wm[rg][1] * acc2[rg][bt][1]
                + wm[rg][2] * acc2[rg][bt][2] + wm[rg][3] * acc2[rg][bt][3];
      out[((size_t)(b * 3072 + u0 + du)) * 256 + n] = val;
    }
  }
}

// ================= launcher =================
extern "C" void kernel_launch(void* const* d_in, const int* in_sizes, int n_in,
                              void* d_out, int out_size, void* d_ws, size_t ws_size,
                              hipStream_t stream) {
  const float* q  = (const float*)d_in[0];
  const float* k  = (const float*)d_in[1];
  const float* wq = (const float*)d_in[2];
  const float* wv = (const float*)d_in[3];
  const float* bv = (const float*)d_in[4];
  const float* wm = (const float*)d_in[5];
  const float* bm = (const float*)d_in[6];
  const float* wo = (const float*)d_in[7];
  const float* bo = (const float*)d_in[8];
  const float* lg = (const float*)d_in[9];
  const float* lb = (const float*)d_in[10];
  const float* wa = (const float*)d_in[11];
  const float* ba = (const float*)d_in[12];
  char* wsb = (char*)d_ws;

  cvtw_kernel<<<448, 256, 0, stream>>>(wq, wv, wm, wo, wsb);
  proj_kernel<<<768, 256, 0, stream>>>(q, k, bv, wsb);
  attn_kernel<<<768, 256, 0, stream>>>(wsb);
  ffn_kernel<<<768, 256, 0, stream>>>(wsb, bm, bo, lg, lb, wa, ba, (float*)d_out);
}